// Round 2
// baseline (642.078 us; speedup 1.0000x reference)
//
#include <hip/hip_runtime.h>
#include <hip/hip_bf16.h>

// SparseFFN: B=4, L=4096, D=1024, E=64, CHUNK=128 -> 128 chunks, top-2 experts.
// R2: W pre-transposed to bf16 [e][n][k] (fits LLC), MFMA-native LDS layout
// (stride-1 ds_read_b128, zero bank conflicts), fused router-sum + x cvt.

#define BD 4
#define LD 4096
#define DD 1024
#define ED 64
#define CHUNKD 128
#define NBITS 6
#define NCHUNK 128   // B * L/CHUNK

typedef __bf16 bf16_8 __attribute__((ext_vector_type(8)));
typedef __bf16 bf16_4 __attribute__((ext_vector_type(4)));
typedef float floatx4 __attribute__((ext_vector_type(4)));

// ---------------- fused: x -> bf16 A, plus per-chunk fp64 column sums --------
// grid = NCHUNK*8, block covers 16 tokens; thread t handles dims t*4..t*4+3.
__global__ __launch_bounds__(256) void sum_cvt_kernel(
    const float* __restrict__ x, __bf16* __restrict__ a, double* __restrict__ csum)
{
    const int chunk = blockIdx.x >> 3;
    const int tg = blockIdx.x & 7;
    const size_t base = (size_t)chunk * CHUNKD * DD + (size_t)tg * 16 * DD;
    const float* xc = x + base;
    __bf16* ac = a + base;
    const int t = threadIdx.x;

    double s0 = 0, s1 = 0, s2 = 0, s3 = 0;
    #pragma unroll 4
    for (int tok = 0; tok < 16; ++tok) {
        const float4 v = *(const float4*)(xc + tok * DD + t * 4);
        bf16_4 o;
        o[0] = (__bf16)v.x; o[1] = (__bf16)v.y; o[2] = (__bf16)v.z; o[3] = (__bf16)v.w;
        *(bf16_4*)(ac + tok * DD + t * 4) = o;
        s0 += (double)v.x; s1 += (double)v.y; s2 += (double)v.z; s3 += (double)v.w;
    }
    double* c = csum + (size_t)chunk * DD + t * 4;
    atomicAdd(c + 0, s0); atomicAdd(c + 1, s1);
    atomicAdd(c + 2, s2); atomicAdd(c + 3, s3);
}

// ---------------- router stage 2: proj + expert pick ----------------
__global__ __launch_bounds__(256) void router2_kernel(
    const double* __restrict__ csum, const float* __restrict__ hyp,
    int* __restrict__ eidx)
{
    const int chunk = blockIdx.x;
    const int t = threadIdx.x;
    double pj[NBITS];
    #pragma unroll
    for (int j = 0; j < NBITS; ++j) pj[j] = 0.0;
    #pragma unroll
    for (int i = 0; i < 4; ++i) {
        const int d = t + i * 256;
        const double emb = csum[(size_t)chunk * DD + d] * (1.0 / 128.0);
        #pragma unroll
        for (int j = 0; j < NBITS; ++j)
            pj[j] += emb * (double)hyp[d * NBITS + j];
    }
    #pragma unroll
    for (int off = 32; off > 0; off >>= 1) {
        #pragma unroll
        for (int j = 0; j < NBITS; ++j)
            pj[j] += __shfl_down(pj[j], off, 64);
    }
    __shared__ double red[4][NBITS];
    const int wave = t >> 6, lane = t & 63;
    if (lane == 0) {
        #pragma unroll
        for (int j = 0; j < NBITS; ++j) red[wave][j] = pj[j];
    }
    __syncthreads();
    if (t == 0) {
        int e1 = 0, weakest = 0;
        double best = 1e300;
        #pragma unroll
        for (int j = 0; j < NBITS; ++j) {
            double p = red[0][j] + red[1][j] + red[2][j] + red[3][j];
            if (p > 0.0) e1 |= (1 << j);
            double aa = fabs(p);
            if (aa < best) { best = aa; weakest = j; }  // first-min, like argmin
        }
        eidx[chunk * 2 + 0] = e1;
        eidx[chunk * 2 + 1] = e1 ^ (1 << weakest);
    }
}

// ---------------- W fp32 [e][k][n] -> bf16 transposed Wt [e][n][k] ----------
// grid = ED * 16; block handles 64 n-rows, full k. threads = 64 n x 4 kc.
__global__ __launch_bounds__(256) void wcvt_kernel(
    const float* __restrict__ W, __bf16* __restrict__ Wt)
{
    const int e = blockIdx.x >> 4;
    const int n0 = (blockIdx.x & 15) * 64;
    const float* We = W + (size_t)e * DD * DD;
    __bf16* Wte = Wt + (size_t)e * DD * DD;
    const int nl = threadIdx.x & 63;
    const int kc = threadIdx.x >> 6;          // 0..3
    const int n = n0 + nl;

    for (int it = 0; it < 32; ++it) {
        const int k = it * 32 + kc * 8;
        float v[8];
        #pragma unroll
        for (int j = 0; j < 8; ++j) v[j] = We[(size_t)(k + j) * DD + n];  // coalesced over nl
        bf16_8 o;
        #pragma unroll
        for (int j = 0; j < 8; ++j) o[j] = (__bf16)v[j];
        *(bf16_8*)(&Wte[(size_t)n * DD + k]) = o;
    }
}

// ---------------- GEMM (bf16 A, bf16 Wt): out = 0.5*(A@W[e1] + A@W[e2]) ----
// MFMA-native LDS layout: tile stored as [row-block rb][lane][16B] so every
// frag read is ds_read_b128 at (base + lane*16) -> conflict-free.
__global__ __launch_bounds__(256) void ffn_gemm_bf16(
    const __bf16* __restrict__ Abf,      // [NCHUNK*128, 1024]
    const __bf16* __restrict__ Wt,       // [64][n=1024][k=1024]
    const int* __restrict__ eidx,
    float* __restrict__ out)
{
    __shared__ __bf16 Als[128 * 32];     // 8 blocks x 64 lanes x 8 elems
    __shared__ __bf16 Bls[128 * 32];

    const int bx = blockIdx.x;
    const int chunk = bx >> 3;
    const int n0 = (bx & 7) * 128;
    const int t = threadIdx.x;
    const int lane = t & 63;
    const int wave = t >> 6;
    const int wm = wave >> 1;
    const int wn = wave & 1;
    const int lr = lane & 15;
    const int q  = lane >> 4;

    const int ee[2] = {eidx[chunk * 2 + 0], eidx[chunk * 2 + 1]};

    const __bf16* Ag = Abf + (size_t)chunk * CHUNKD * DD;

    floatx4 acc[4][4] = {};

    for (int xp = 0; xp < 2; ++xp) {
        const __bf16* Bg = Wt + (size_t)ee[xp] * (DD * DD) + (size_t)n0 * DD;
        for (int k0 = 0; k0 < DD; k0 += 32) {
            // stage A row-blocks (each issue = one 16-row x 32-k MFMA block)
            #pragma unroll
            for (int i = 0; i < 2; ++i) {
                const int rb = wave * 2 + i;
                const __bf16* ga = Ag + (size_t)(rb * 16 + lr) * DD + k0 + q * 8;
                __builtin_amdgcn_global_load_lds(
                    (const __attribute__((address_space(1))) void*)ga,
                    (__attribute__((address_space(3))) void*)(&Als[rb * 512]),
                    16, 0, 0);
            }
            // stage B row-blocks (n-rows of Wt, k-contiguous)
            #pragma unroll
            for (int i = 0; i < 2; ++i) {
                const int rb = wave * 2 + i;
                const __bf16* gb = Bg + (size_t)(rb * 16 + lr) * DD + k0 + q * 8;
                __builtin_amdgcn_global_load_lds(
                    (const __attribute__((address_space(1))) void*)gb,
                    (__attribute__((address_space(3))) void*)(&Bls[rb * 512]),
                    16, 0, 0);
            }
            __syncthreads();

            bf16_8 af[4], bfr[4];
            #pragma unroll
            for (int mt = 0; mt < 4; ++mt)
                af[mt] = *(const bf16_8*)(&Als[(wm * 4 + mt) * 512 + lane * 8]);
            #pragma unroll
            for (int nt = 0; nt < 4; ++nt)
                bfr[nt] = *(const bf16_8*)(&Bls[(wn * 4 + nt) * 512 + lane * 8]);
            #pragma unroll
            for (int mt = 0; mt < 4; ++mt) {
                #pragma unroll
                for (int nt = 0; nt < 4; ++nt)
                    acc[mt][nt] = __builtin_amdgcn_mfma_f32_16x16x32_bf16(
                        af[mt], bfr[nt], acc[mt][nt], 0, 0, 0);
            }
            __syncthreads();
        }
    }

    const size_t orow0 = (size_t)chunk * CHUNKD;
    #pragma unroll
    for (int mt = 0; mt < 4; ++mt) {
        #pragma unroll
        for (int nt = 0; nt < 4; ++nt) {
            const int col = n0 + wn * 64 + nt * 16 + lr;
            #pragma unroll
            for (int r = 0; r < 4; ++r) {
                const int row = wm * 64 + mt * 16 + q * 4 + r;
                out[(orow0 + row) * DD + col] = acc[mt][nt][r] * 0.5f;
            }
        }
    }
}

// ======================= fallback path (R1, needs only ~34 MB ws) ===========
__global__ __launch_bounds__(256) void router_kernel(
    const float* __restrict__ x, const float* __restrict__ hyp,
    int* __restrict__ eidx)
{
    const int chunk = blockIdx.x;
    const int t = threadIdx.x;
    const float* xc = x + (size_t)chunk * CHUNKD * DD;
    double cs[4] = {0.0, 0.0, 0.0, 0.0};
    for (int tok = 0; tok < CHUNKD; ++tok) {
        const float* row = xc + tok * DD;
        #pragma unroll
        for (int i = 0; i < 4; ++i) cs[i] += (double)row[t + i * 256];
    }
    double pj[NBITS];
    #pragma unroll
    for (int j = 0; j < NBITS; ++j) pj[j] = 0.0;
    #pragma unroll
    for (int i = 0; i < 4; ++i) {
        const int d = t + i * 256;
        const double emb = cs[i] * (1.0 / 128.0);
        #pragma unroll
        for (int j = 0; j < NBITS; ++j) pj[j] += emb * (double)hyp[d * NBITS + j];
    }
    #pragma unroll
    for (int off = 32; off > 0; off >>= 1) {
        #pragma unroll
        for (int j = 0; j < NBITS; ++j) pj[j] += __shfl_down(pj[j], off, 64);
    }
    __shared__ double red[4][NBITS];
    const int wave = t >> 6, lane = t & 63;
    if (lane == 0) {
        #pragma unroll
        for (int j = 0; j < NBITS; ++j) red[wave][j] = pj[j];
    }
    __syncthreads();
    if (t == 0) {
        int e1 = 0, weakest = 0;
        double best = 1e300;
        #pragma unroll
        for (int j = 0; j < NBITS; ++j) {
            double p = red[0][j] + red[1][j] + red[2][j] + red[3][j];
            if (p > 0.0) e1 |= (1 << j);
            double a = fabs(p);
            if (a < best) { best = a; weakest = j; }
        }
        eidx[chunk * 2 + 0] = e1;
        eidx[chunk * 2 + 1] = e1 ^ (1 << weakest);
    }
}

__global__ __launch_bounds__(256) void cvt_x_kernel(
    const float* __restrict__ x, __bf16* __restrict__ a)
{
    const size_t i = ((size_t)blockIdx.x * 256 + threadIdx.x) * 4;
    const float4 v = *(const float4*)(x + i);
    bf16_4 o;
    o[0] = (__bf16)v.x; o[1] = (__bf16)v.y; o[2] = (__bf16)v.z; o[3] = (__bf16)v.w;
    *(bf16_4*)(a + i) = o;
}

__global__ __launch_bounds__(256) void ffn_gemm_fp32w(
    const __bf16* __restrict__ Abf, const float* __restrict__ W,
    const int* __restrict__ eidx, float* __restrict__ out)
{
    __shared__ __bf16 Als[128 * 32];
    __shared__ __bf16 Bls[128 * 32];
    const int bx = blockIdx.x;
    const int chunk = bx >> 3;
    const int n0 = (bx & 7) * 128;
    const int t = threadIdx.x;
    const int lane = t & 63;
    const int wave = t >> 6;
    const int wm = wave >> 1;
    const int wn = wave & 1;
    const int lr = lane & 15;
    const int q  = lane >> 4;
    const int ee[2] = {eidx[chunk * 2 + 0], eidx[chunk * 2 + 1]};
    const __bf16* Ag = Abf + (size_t)chunk * CHUNKD * DD;
    const int a_col = (lane & 3) * 8;
    const int a_rsub = lane >> 2;
    floatx4 acc[4][4] = {};
    for (int xp = 0; xp < 2; ++xp) {
        const float* We = W + (size_t)ee[xp] * (DD * DD) + n0;
        for (int k0 = 0; k0 < DD; k0 += 32) {
            float bv[2][8];
            #pragma unroll
            for (int rep = 0; rep < 2; ++rep) {
                const int nb = wave * 16 + lr + rep * 64;
                const float* src = We + (size_t)(k0 + q * 8) * DD + nb;
                #pragma unroll
                for (int j = 0; j < 8; ++j) bv[rep][j] = src[(size_t)j * DD];
            }
            #pragma unroll
            for (int i = 0; i < 2; ++i) {
                const __bf16* ga = Ag + (size_t)((wave * 2 + i) * 16 + a_rsub) * DD + k0 + a_col;
                __builtin_amdgcn_global_load_lds(
                    (const __attribute__((address_space(1))) void*)ga,
                    (__attribute__((address_space(3))) void*)(&Als[(wave * 2 + i) * 512]),
                    16, 0, 0);
            }
            #pragma unroll
            for (int rep = 0; rep < 2; ++rep) {
                const int nb = wave * 16 + lr + rep * 64;
                bf16_8 bw;
                #pragma unroll
                for (int j = 0; j < 8; ++j) bw[j] = (__bf16)bv[rep][j];
                *(bf16_8*)(&Bls[nb * 32 + q * 8]) = bw;
            }
            __syncthreads();
            bf16_8 af[4], bfr[4];
            #pragma unroll
            for (int mt = 0; mt < 4; ++mt)
                af[mt] = *(const bf16_8*)(&Als[(wm * 64 + mt * 16 + lr) * 32 + q * 8]);
            #pragma unroll
            for (int nt = 0; nt < 4; ++nt)
                bfr[nt] = *(const bf16_8*)(&Bls[(wn * 64 + nt * 16 + lr) * 32 + q * 8]);
            #pragma unroll
            for (int mt = 0; mt < 4; ++mt) {
                #pragma unroll
                for (int nt = 0; nt < 4; ++nt)
                    acc[mt][nt] = __builtin_amdgcn_mfma_f32_16x16x32_bf16(
                        af[mt], bfr[nt], acc[mt][nt], 0, 0, 0);
            }
            __syncthreads();
        }
    }
    const size_t orow0 = (size_t)chunk * CHUNKD;
    #pragma unroll
    for (int mt = 0; mt < 4; ++mt) {
        #pragma unroll
        for (int nt = 0; nt < 4; ++nt) {
            const int col = n0 + wn * 64 + nt * 16 + lr;
            #pragma unroll
            for (int r = 0; r < 4; ++r) {
                const int row = wm * 64 + mt * 16 + q * 4 + r;
                out[(orow0 + row) * DD + col] = acc[mt][nt][r] * 0.5f;
            }
        }
    }
}

extern "C" void kernel_launch(void* const* d_in, const int* in_sizes, int n_in,
                              void* d_out, int out_size, void* d_ws, size_t ws_size,
                              hipStream_t stream) {
    const float* x   = (const float*)d_in[0];   // [4,4096,1024]
    const float* W   = (const float*)d_in[1];   // [64,1024,1024]
    const float* hyp = (const float*)d_in[2];   // [1024,6]
    float* out = (float*)d_out;

    // ws layout (fast path): eidx 1KB | csum 1MB | A bf16 33.5MB | Wt bf16 128MB
    const size_t off_eidx = 0;
    const size_t off_csum = 4096;
    const size_t off_a    = off_csum + (size_t)NCHUNK * DD * 8;
    const size_t off_wt   = off_a + (size_t)NCHUNK * CHUNKD * DD * 2;
    const size_t need     = off_wt + (size_t)ED * DD * DD * 2;

    int* eidx = (int*)((char*)d_ws + off_eidx);
    __bf16* Abf = (__bf16*)((char*)d_ws + off_a);

    if (ws_size >= need) {
        double* csum = (double*)((char*)d_ws + off_csum);
        __bf16* Wtb = (__bf16*)((char*)d_ws + off_wt);
        hipMemsetAsync(csum, 0, (size_t)NCHUNK * DD * 8, stream);
        sum_cvt_kernel<<<NCHUNK * 8, 256, 0, stream>>>(x, Abf, csum);
        wcvt_kernel<<<ED * 16, 256, 0, stream>>>(W, Wtb);
        router2_kernel<<<NCHUNK, 256, 0, stream>>>(csum, hyp, eidx);
        ffn_gemm_bf16<<<NCHUNK * 8, 256, 0, stream>>>(Abf, Wtb, eidx, out);
    } else {
        // fallback: R1 path (ws >= ~34 MB)
        __bf16* Abf2 = (__bf16*)((char*)d_ws + 1024);
        router_kernel<<<NCHUNK, 256, 0, stream>>>(x, hyp, eidx);
        cvt_x_kernel<<<(BD * LD * DD) / (256 * 4), 256, 0, stream>>>(x, Abf2);
        ffn_gemm_fp32w<<<NCHUNK * 8, 256, 0, stream>>>(Abf2, W, eidx, out);
    }
}

// Round 3
// 542.102 us; speedup vs baseline: 1.1844x; 1.1844x over previous
//
#include <hip/hip_runtime.h>
#include <hip/hip_bf16.h>

// SparseFFN R3: dual-expert K-loop GEMM (32 MFMA/barrier, A staged once),
// Wt stored in GEMM-tile order so every global_load_lds is contiguous 1 KB;
// wcvt via LDS-tiled transpose (coalesced reads AND writes).

#define BD 4
#define LD 4096
#define DD 1024
#define ED 64
#define CHUNKD 128
#define NBITS 6
#define NCHUNK 128   // B * L/CHUNK

typedef __bf16 bf16_8 __attribute__((ext_vector_type(8)));
typedef __bf16 bf16_4 __attribute__((ext_vector_type(4)));
typedef float floatx4 __attribute__((ext_vector_type(4)));

// Wt tile-order cell: [e][nt(8)][s(32)][rb(8)][lane(64)] x 8 bf16 (16B).
// cell(e,nt,s,rb,l) holds W[e][k = s*32 + (l>>4)*8 + j][n = nt*128 + rb*16 + (l&15)], j=0..7
#define WT_PER_ENT  131072          // 32*8*64*8 elems = 256 KB per (e,nt)

// ---------------- fused: x -> bf16 A (row-major), per-chunk fp64 col sums ---
__global__ __launch_bounds__(256) void sum_cvt_kernel(
    const float* __restrict__ x, __bf16* __restrict__ a, double* __restrict__ csum)
{
    const int chunk = blockIdx.x >> 3;
    const int tg = blockIdx.x & 7;
    const size_t base = (size_t)chunk * CHUNKD * DD + (size_t)tg * 16 * DD;
    const float* xc = x + base;
    __bf16* ac = a + base;
    const int t = threadIdx.x;

    double s0 = 0, s1 = 0, s2 = 0, s3 = 0;
    #pragma unroll 4
    for (int tok = 0; tok < 16; ++tok) {
        const float4 v = *(const float4*)(xc + tok * DD + t * 4);
        bf16_4 o;
        o[0] = (__bf16)v.x; o[1] = (__bf16)v.y; o[2] = (__bf16)v.z; o[3] = (__bf16)v.w;
        *(bf16_4*)(ac + tok * DD + t * 4) = o;
        s0 += (double)v.x; s1 += (double)v.y; s2 += (double)v.z; s3 += (double)v.w;
    }
    double* c = csum + (size_t)chunk * DD + t * 4;
    atomicAdd(c + 0, s0); atomicAdd(c + 1, s1);
    atomicAdd(c + 2, s2); atomicAdd(c + 3, s3);
}

// ---------------- router stage 2: proj + expert pick ----------------
__global__ __launch_bounds__(256) void router2_kernel(
    const double* __restrict__ csum, const float* __restrict__ hyp,
    int* __restrict__ eidx)
{
    const int chunk = blockIdx.x;
    const int t = threadIdx.x;
    double pj[NBITS];
    #pragma unroll
    for (int j = 0; j < NBITS; ++j) pj[j] = 0.0;
    #pragma unroll
    for (int i = 0; i < 4; ++i) {
        const int d = t + i * 256;
        const double emb = csum[(size_t)chunk * DD + d] * (1.0 / 128.0);
        #pragma unroll
        for (int j = 0; j < NBITS; ++j)
            pj[j] += emb * (double)hyp[d * NBITS + j];
    }
    #pragma unroll
    for (int off = 32; off > 0; off >>= 1) {
        #pragma unroll
        for (int j = 0; j < NBITS; ++j)
            pj[j] += __shfl_down(pj[j], off, 64);
    }
    __shared__ double red[4][NBITS];
    const int wave = t >> 6, lane = t & 63;
    if (lane == 0) {
        #pragma unroll
        for (int j = 0; j < NBITS; ++j) red[wave][j] = pj[j];
    }
    __syncthreads();
    if (t == 0) {
        int e1 = 0, weakest = 0;
        double best = 1e300;
        #pragma unroll
        for (int j = 0; j < NBITS; ++j) {
            double p = red[0][j] + red[1][j] + red[2][j] + red[3][j];
            if (p > 0.0) e1 |= (1 << j);
            double aa = fabs(p);
            if (aa < best) { best = aa; weakest = j; }  // first-min, like argmin
        }
        eidx[chunk * 2 + 0] = e1;
        eidx[chunk * 2 + 1] = e1 ^ (1 << weakest);
    }
}

// ---------------- W fp32 [e][k][n] -> bf16 Wt in GEMM-tile order ------------
// grid = 64e * 8nt * 2kh. Per iter: stage 32k x 128n fp32 tile in LDS
// (coalesced float4 reads), emit 512 cells (contiguous 1KB wave writes).
__global__ __launch_bounds__(256) void wcvt_kernel(
    const float* __restrict__ W, __bf16* __restrict__ WtSw)
{
    __shared__ float tile[32 * 129];

    const int bx = blockIdx.x;
    const int kh = bx & 1;
    const int nt = (bx >> 1) & 7;
    const int e  = bx >> 4;
    const int t = threadIdx.x;

    const float* We = W + (size_t)e * DD * DD + nt * 128;
    __bf16* base_ent = WtSw + (size_t)(e * 8 + nt) * WT_PER_ENT;

    for (int it = 0; it < 16; ++it) {
        const int k0 = kh * 512 + it * 32;
        const int s  = kh * 16 + it;
        // phase 1: read 32x128 fp32, coalesced float4
        #pragma unroll
        for (int p = 0; p < 4; ++p) {
            const int idx = p * 256 + t;
            const int kr  = idx >> 5;
            const int nc4 = idx & 31;
            const float4 v = *(const float4*)(We + (size_t)(k0 + kr) * DD + nc4 * 4);
            float* dst = &tile[kr * 129 + nc4 * 4];
            dst[0] = v.x; dst[1] = v.y; dst[2] = v.z; dst[3] = v.w;
        }
        __syncthreads();
        // phase 2: emit cells; per wave: 64 consecutive lanes -> 1KB contiguous
        #pragma unroll
        for (int c = 0; c < 2; ++c) {
            const int cell = c * 256 + t;
            const int l  = cell & 63;
            const int rb = cell >> 6;
            const int q  = l >> 4;
            const int lr = l & 15;
            bf16_8 o;
            #pragma unroll
            for (int j = 0; j < 8; ++j)
                o[j] = (__bf16)tile[(q * 8 + j) * 129 + rb * 16 + lr];
            *(bf16_8*)(base_ent + ((size_t)s * 8 + rb) * 512 + l * 8) = o;
        }
        __syncthreads();
    }
}

// ---------------- GEMM dual-expert: out = 0.5*(A@W[e0] + A@W[e1]) -----------
__global__ __launch_bounds__(256) void ffn_gemm_bf16(
    const __bf16* __restrict__ Abf,      // [NCHUNK*128, 1024] row-major
    const __bf16* __restrict__ WtSw,     // tile-order (see above)
    const int* __restrict__ eidx,
    float* __restrict__ out)
{
    __shared__ __bf16 Als[8 * 512];      // 8 KB
    __shared__ __bf16 B0ls[8 * 512];     // 8 KB
    __shared__ __bf16 B1ls[8 * 512];     // 8 KB

    const int bx = blockIdx.x;
    const int chunk = bx >> 3;
    const int ntb = bx & 7;
    const int t = threadIdx.x;
    const int lane = t & 63;
    const int wave = t >> 6;
    const int wm = wave >> 1;
    const int wn = wave & 1;
    const int lr = lane & 15;
    const int q  = lane >> 4;

    const int e0 = eidx[chunk * 2 + 0];
    const int e1 = eidx[chunk * 2 + 1];

    const __bf16* Ag = Abf + (size_t)chunk * CHUNKD * DD;
    const __bf16* Bg0 = WtSw + (size_t)(e0 * 8 + ntb) * WT_PER_ENT + lane * 8;
    const __bf16* Bg1 = WtSw + (size_t)(e1 * 8 + ntb) * WT_PER_ENT + lane * 8;

    // A issue source for this wave's two row-blocks
    const int rb0 = wave * 2;
    const __bf16* AgW0 = Ag + (size_t)(rb0 * 16 + lr) * DD + q * 8;
    const __bf16* AgW1 = Ag + (size_t)((rb0 + 1) * 16 + lr) * DD + q * 8;

    floatx4 acc[4][4] = {};

    for (int ks = 0; ks < 32; ++ks) {
        const int k0 = ks * 32;
        // A: 2 issues/wave (64B-segmented, L2/LLC-hot)
        __builtin_amdgcn_global_load_lds(
            (const __attribute__((address_space(1))) void*)(AgW0 + k0),
            (__attribute__((address_space(3))) void*)(&Als[rb0 * 512]), 16, 0, 0);
        __builtin_amdgcn_global_load_lds(
            (const __attribute__((address_space(1))) void*)(AgW1 + k0),
            (__attribute__((address_space(3))) void*)(&Als[(rb0 + 1) * 512]), 16, 0, 0);
        // B0/B1: 2 issues/wave each, fully contiguous 1 KB per issue
        #pragma unroll
        for (int i = 0; i < 2; ++i) {
            const int rb = rb0 + i;
            __builtin_amdgcn_global_load_lds(
                (const __attribute__((address_space(1))) void*)(Bg0 + ((size_t)ks * 8 + rb) * 512),
                (__attribute__((address_space(3))) void*)(&B0ls[rb * 512]), 16, 0, 0);
            __builtin_amdgcn_global_load_lds(
                (const __attribute__((address_space(1))) void*)(Bg1 + ((size_t)ks * 8 + rb) * 512),
                (__attribute__((address_space(3))) void*)(&B1ls[rb * 512]), 16, 0, 0);
        }
        __syncthreads();

        bf16_8 af[4], bb[4];
        #pragma unroll
        for (int mt = 0; mt < 4; ++mt)
            af[mt] = *(const bf16_8*)(&Als[(wm * 4 + mt) * 512 + lane * 8]);
        #pragma unroll
        for (int nt = 0; nt < 4; ++nt)
            bb[nt] = *(const bf16_8*)(&B0ls[(wn * 4 + nt) * 512 + lane * 8]);
        #pragma unroll
        for (int mt = 0; mt < 4; ++mt) {
            #pragma unroll
            for (int nt = 0; nt < 4; ++nt)
                acc[mt][nt] = __builtin_amdgcn_mfma_f32_16x16x32_bf16(
                    af[mt], bb[nt], acc[mt][nt], 0, 0, 0);
        }
        #pragma unroll
        for (int nt = 0; nt < 4; ++nt)
            bb[nt] = *(const bf16_8*)(&B1ls[(wn * 4 + nt) * 512 + lane * 8]);
        #pragma unroll
        for (int mt = 0; mt < 4; ++mt) {
            #pragma unroll
            for (int nt = 0; nt < 4; ++nt)
                acc[mt][nt] = __builtin_amdgcn_mfma_f32_16x16x32_bf16(
                    af[mt], bb[nt], acc[mt][nt], 0, 0, 0);
        }
        __syncthreads();
    }

    const size_t orow0 = (size_t)chunk * CHUNKD;
    const int n0 = ntb * 128;
    #pragma unroll
    for (int mt = 0; mt < 4; ++mt) {
        #pragma unroll
        for (int nt = 0; nt < 4; ++nt) {
            const int col = n0 + wn * 64 + nt * 16 + lr;
            #pragma unroll
            for (int r = 0; r < 4; ++r) {
                const int row = wm * 64 + mt * 16 + q * 4 + r;
                out[(orow0 + row) * DD + col] = acc[mt][nt][r] * 0.5f;
            }
        }
    }
}

// ======================= fallback path (R1-style, ~34 MB ws) ================
__global__ __launch_bounds__(256) void router_kernel(
    const float* __restrict__ x, const float* __restrict__ hyp,
    int* __restrict__ eidx)
{
    const int chunk = blockIdx.x;
    const int t = threadIdx.x;
    const float* xc = x + (size_t)chunk * CHUNKD * DD;
    double cs[4] = {0.0, 0.0, 0.0, 0.0};
    for (int tok = 0; tok < CHUNKD; ++tok) {
        const float* row = xc + tok * DD;
        #pragma unroll
        for (int i = 0; i < 4; ++i) cs[i] += (double)row[t + i * 256];
    }
    double pj[NBITS];
    #pragma unroll
    for (int j = 0; j < NBITS; ++j) pj[j] = 0.0;
    #pragma unroll
    for (int i = 0; i < 4; ++i) {
        const int d = t + i * 256;
        const double emb = cs[i] * (1.0 / 128.0);
        #pragma unroll
        for (int j = 0; j < NBITS; ++j) pj[j] += emb * (double)hyp[d * NBITS + j];
    }
    #pragma unroll
    for (int off = 32; off > 0; off >>= 1) {
        #pragma unroll
        for (int j = 0; j < NBITS; ++j) pj[j] += __shfl_down(pj[j], off, 64);
    }
    __shared__ double red[4][NBITS];
    const int wave = t >> 6, lane = t & 63;
    if (lane == 0) {
        #pragma unroll
        for (int j = 0; j < NBITS; ++j) red[wave][j] = pj[j];
    }
    __syncthreads();
    if (t == 0) {
        int e1 = 0, weakest = 0;
        double best = 1e300;
        #pragma unroll
        for (int j = 0; j < NBITS; ++j) {
            double p = red[0][j] + red[1][j] + red[2][j] + red[3][j];
            if (p > 0.0) e1 |= (1 << j);
            double a = fabs(p);
            if (a < best) { best = a; weakest = j; }
        }
        eidx[chunk * 2 + 0] = e1;
        eidx[chunk * 2 + 1] = e1 ^ (1 << weakest);
    }
}

__global__ __launch_bounds__(256) void cvt_x_kernel(
    const float* __restrict__ x, __bf16* __restrict__ a)
{
    const size_t i = ((size_t)blockIdx.x * 256 + threadIdx.x) * 4;
    const float4 v = *(const float4*)(x + i);
    bf16_4 o;
    o[0] = (__bf16)v.x; o[1] = (__bf16)v.y; o[2] = (__bf16)v.z; o[3] = (__bf16)v.w;
    *(bf16_4*)(a + i) = o;
}

__global__ __launch_bounds__(256) void ffn_gemm_fp32w(
    const __bf16* __restrict__ Abf, const float* __restrict__ W,
    const int* __restrict__ eidx, float* __restrict__ out)
{
    __shared__ __bf16 Als[128 * 32];
    __shared__ __bf16 Bls[128 * 32];
    const int bx = blockIdx.x;
    const int chunk = bx >> 3;
    const int n0 = (bx & 7) * 128;
    const int t = threadIdx.x;
    const int lane = t & 63;
    const int wave = t >> 6;
    const int wm = wave >> 1;
    const int wn = wave & 1;
    const int lr = lane & 15;
    const int q  = lane >> 4;
    const int ee[2] = {eidx[chunk * 2 + 0], eidx[chunk * 2 + 1]};
    const __bf16* Ag = Abf + (size_t)chunk * CHUNKD * DD;
    const int a_col = (lane & 3) * 8;
    const int a_rsub = lane >> 2;
    floatx4 acc[4][4] = {};
    for (int xp = 0; xp < 2; ++xp) {
        const float* We = W + (size_t)ee[xp] * (DD * DD) + n0;
        for (int k0 = 0; k0 < DD; k0 += 32) {
            float bv[2][8];
            #pragma unroll
            for (int rep = 0; rep < 2; ++rep) {
                const int nb = wave * 16 + lr + rep * 64;
                const float* src = We + (size_t)(k0 + q * 8) * DD + nb;
                #pragma unroll
                for (int j = 0; j < 8; ++j) bv[rep][j] = src[(size_t)j * DD];
            }
            #pragma unroll
            for (int i = 0; i < 2; ++i) {
                const __bf16* ga = Ag + (size_t)((wave * 2 + i) * 16 + a_rsub) * DD + k0 + a_col;
                __builtin_amdgcn_global_load_lds(
                    (const __attribute__((address_space(1))) void*)ga,
                    (__attribute__((address_space(3))) void*)(&Als[(wave * 2 + i) * 512]),
                    16, 0, 0);
            }
            #pragma unroll
            for (int rep = 0; rep < 2; ++rep) {
                const int nb = wave * 16 + lr + rep * 64;
                bf16_8 bw;
                #pragma unroll
                for (int j = 0; j < 8; ++j) bw[j] = (__bf16)bv[rep][j];
                *(bf16_8*)(&Bls[nb * 32 + q * 8]) = bw;
            }
            __syncthreads();
            bf16_8 af[4], bfr[4];
            #pragma unroll
            for (int mt = 0; mt < 4; ++mt)
                af[mt] = *(const bf16_8*)(&Als[(wm * 64 + mt * 16 + lr) * 32 + q * 8]);
            #pragma unroll
            for (int nt = 0; nt < 4; ++nt)
                bfr[nt] = *(const bf16_8*)(&Bls[(wn * 64 + nt * 16 + lr) * 32 + q * 8]);
            #pragma unroll
            for (int mt = 0; mt < 4; ++mt) {
                #pragma unroll
                for (int nt = 0; nt < 4; ++nt)
                    acc[mt][nt] = __builtin_amdgcn_mfma_f32_16x16x32_bf16(
                        af[mt], bfr[nt], acc[mt][nt], 0, 0, 0);
            }
            __syncthreads();
        }
    }
    const size_t orow0 = (size_t)chunk * CHUNKD;
    #pragma unroll
    for (int mt = 0; mt < 4; ++mt) {
        #pragma unroll
        for (int nt = 0; nt < 4; ++nt) {
            const int col = n0 + wn * 64 + nt * 16 + lr;
            #pragma unroll
            for (int r = 0; r < 4; ++r) {
                const int row = wm * 64 + mt * 16 + q * 4 + r;
                out[(orow0 + row) * DD + col] = acc[mt][nt][r] * 0.5f;
            }
        }
    }
}

extern "C" void kernel_launch(void* const* d_in, const int* in_sizes, int n_in,
                              void* d_out, int out_size, void* d_ws, size_t ws_size,
                              hipStream_t stream) {
    const float* x   = (const float*)d_in[0];   // [4,4096,1024]
    const float* W   = (const float*)d_in[1];   // [64,1024,1024]
    const float* hyp = (const float*)d_in[2];   // [1024,6]
    float* out = (float*)d_out;

    // ws layout: eidx 4KB | csum 1MB | A bf16 33.5MB | WtSw bf16 128MB
    const size_t off_eidx = 0;
    const size_t off_csum = 4096;
    const size_t off_a    = off_csum + (size_t)NCHUNK * DD * 8;
    const size_t off_wt   = off_a + (size_t)NCHUNK * CHUNKD * DD * 2;
    const size_t need     = off_wt + (size_t)ED * DD * DD * 2;

    int* eidx = (int*)((char*)d_ws + off_eidx);
    __bf16* Abf = (__bf16*)((char*)d_ws + off_a);

    if (ws_size >= need) {
        double* csum = (double*)((char*)d_ws + off_csum);
        __bf16* WtSw = (__bf16*)((char*)d_ws + off_wt);
        hipMemsetAsync(csum, 0, (size_t)NCHUNK * DD * 8, stream);
        sum_cvt_kernel<<<NCHUNK * 8, 256, 0, stream>>>(x, Abf, csum);
        wcvt_kernel<<<ED * 16, 256, 0, stream>>>(W, WtSw);
        router2_kernel<<<NCHUNK, 256, 0, stream>>>(csum, hyp, eidx);
        ffn_gemm_bf16<<<NCHUNK * 8, 256, 0, stream>>>(Abf, WtSw, eidx, out);
    } else {
        __bf16* Abf2 = (__bf16*)((char*)d_ws + 1024);
        router_kernel<<<NCHUNK, 256, 0, stream>>>(x, hyp, eidx);
        cvt_x_kernel<<<(BD * LD * DD) / (256 * 4), 256, 0, stream>>>(x, Abf2);
        ffn_gemm_fp32w<<<NCHUNK * 8, 256, 0, stream>>>(Abf2, W, eidx, out);
    }
}